// Round 1
// baseline (383.883 us; speedup 1.0000x reference)
//
#include <hip/hip_runtime.h>
#include <hip/hip_bf16.h>

#define B_ 4
#define N_ 512
#define D_ 128

typedef __attribute__((ext_vector_type(8))) short bf16x8;
typedef __attribute__((ext_vector_type(4))) float f32x4;

__device__ __forceinline__ f32x4 mfma16(bf16x8 a, bf16x8 b, f32x4 c) {
    return __builtin_amdgcn_mfma_f32_16x16x32_bf16(a, b, c, 0, 0, 0);
}

// ---------------- prep 1: transpose weights to [N][K] bf16 ----------------
__global__ void prep_weights_kernel(const float* __restrict__ aW1, const float* __restrict__ aW2,
                                    const float* __restrict__ pW2,
                                    __hip_bfloat16* __restrict__ aW1T, __hip_bfloat16* __restrict__ aW2T,
                                    __hip_bfloat16* __restrict__ pW2T) {
    int idx = blockIdx.x * 256 + threadIdx.x;   // grid covers 32768
    if (idx < 256 * 128) {
        // aW1T[256][128]: aW1T[n][k] = aW1[k][n]; aW1 is [128][256]
        int n = idx >> 7, k = idx & 127;
        aW1T[idx] = __float2bfloat16(aW1[k * 256 + n]);
        // aW2T[128][256]: aW2T[n][k] = aW2[k][n]; aW2 is [256][128]
        int n2 = idx >> 8, k2 = idx & 255;
        aW2T[idx] = __float2bfloat16(aW2[k2 * 128 + n2]);
    }
    if (idx < 128 * 64) {
        // pW2T[128][64]: pW2T[n][k] = pW2[k][n]; pW2 is [64][128]
        int n = idx >> 6, k = idx & 63;
        pW2T[idx] = __float2bfloat16(pW2[k * 128 + n]);
    }
}

// ---------------- prep 2: qkv = x^T @ Wqkv + bqkv ----------------
__global__ void qkv_kernel(const float* __restrict__ x, const float* __restrict__ Wqkv,
                           const float* __restrict__ bqkv,
                           float* __restrict__ q, float* __restrict__ k, float* __restrict__ v) {
    int idx = blockIdx.x * 256 + threadIdx.x;   // B*N*384 = 786432
    if (idx >= B_ * N_ * 384) return;
    int m = idx % 384;
    int bn = idx / 384;
    int n = bn & (N_ - 1), b = bn >> 9;
    const float* xp = x + (b * D_) * N_ + n;
    float acc = bqkv[m];
#pragma unroll 8
    for (int d = 0; d < D_; ++d) acc = fmaf(xp[d * N_], Wqkv[d * 384 + m], acc);
    float* dst = (m < 128) ? q : (m < 256 ? k : v);
    dst[bn * D_ + (m & 127)] = acc;
}

// ---------------- main fused kernel: one block per (b,i) ----------------
__global__ __launch_bounds__(512) void fused_attn_kernel(
    const float* __restrict__ qg, const float* __restrict__ kg, const float* __restrict__ vg,
    const float* __restrict__ pos, const float* __restrict__ pW1, const float* __restrict__ pb1,
    const __hip_bfloat16* __restrict__ pW2T, const float* __restrict__ pb2,
    const __hip_bfloat16* __restrict__ aW1T, const float* __restrict__ ab1,
    const __hip_bfloat16* __restrict__ aW2T, const float* __restrict__ ab2,
    float* __restrict__ out)
{
    __shared__ __hip_bfloat16 rpe_s[64][136];     // 17.4 KB  (pad: 272B rows -> 2-way banks)
    __shared__ __hip_bfloat16 t_s[64][136];       // 17.4 KB  (ph_s aliased on top)
    __shared__ __hip_bfloat16 hid_s[64][264];     // 33.8 KB
    __shared__ float q_s[128];
    __shared__ float pW1_s[192];
    __shared__ float pb1_s[64];

    const int tid = threadIdx.x;
    const int w  = tid >> 6;      // wave 0..7
    const int l  = tid & 63;
    const int lg = l >> 4;        // lane group 0..3
    const int lc = l & 15;        // lane col 0..15

    const int bi = blockIdx.x;
    const int b  = bi >> 9;
    const int i  = bi & (N_ - 1);

    // ---- phase 0: stage small constants ----
    if (tid < 128) q_s[tid] = qg[(b * N_ + i) * D_ + tid];
    if (tid >= 256 && tid < 448) pW1_s[tid - 256] = pW1[tid - 256];
    if (tid >= 448) pb1_s[tid - 448] = pb1[tid - 448];

    const float ab1_0 = ab1[32 * w + lc];
    const float ab1_1 = ab1[32 * w + 16 + lc];
    const float ab2_r = ab2[16 * w + lc];
    const float pb2_r = pb2[16 * w + lc];

    const float pi0 = pos[(b * N_ + i) * 3 + 0];
    const float pi1 = pos[(b * N_ + i) * 3 + 1];
    const float pi2 = pos[(b * N_ + i) * 3 + 2];

    // ---- persistent weight B-fragments (per-wave column ownership) ----
    bf16x8 bw1[2][4], bw2[8], bwp[2];
    {
        const bf16x8* p1 = (const bf16x8*)aW1T;   // [256 rows][16 vec]
#pragma unroll
        for (int nt = 0; nt < 2; ++nt)
#pragma unroll
            for (int ks = 0; ks < 4; ++ks)
                bw1[nt][ks] = p1[(32 * w + 16 * nt + lc) * 16 + ks * 4 + lg];
        const bf16x8* p2 = (const bf16x8*)aW2T;   // [128 rows][32 vec]
#pragma unroll
        for (int ks = 0; ks < 8; ++ks)
            bw2[ks] = p2[(16 * w + lc) * 32 + ks * 4 + lg];
        const bf16x8* pp = (const bf16x8*)pW2T;   // [128 rows][8 vec]
#pragma unroll
        for (int ks = 0; ks < 2; ++ks)
            bwp[ks] = pp[(16 * w + lc) * 8 + ks * 4 + lg];
    }

    float m_run = -1e30f, l_run = 0.f, o_run = 0.f;
    const int dcol = 16 * w + lc;   // this lane's output channel

    __hip_bfloat16 (*ph_s)[72] = (__hip_bfloat16 (*)[72])t_s;   // alias (disjoint in time)

    for (int jt = 0; jt < 8; ++jt) {
        const int jb = jt * 64;
        __syncthreads();   // prev tile's reads of rpe/hid/t done

        // ---- A: pos-MLP layer 1 (VALU): ph[64][64] ----
        {
            int jl = tid >> 3;
            int hb = (tid & 7) * 8;
            int j = jb + jl;
            float pj0 = pos[(b * N_ + j) * 3 + 0];
            float pj1 = pos[(b * N_ + j) * 3 + 1];
            float pj2 = pos[(b * N_ + j) * 3 + 2];
            float r0 = pi0 - pj0, r1 = pi1 - pj1, r2 = pi2 - pj2;
#pragma unroll
            for (int h = 0; h < 8; ++h) {
                int hh = hb + h;
                float a = pb1_s[hh] + r0 * pW1_s[hh] + r1 * pW1_s[64 + hh] + r2 * pW1_s[128 + hh];
                ph_s[jl][hh] = __float2bfloat16(fmaxf(a, 0.f));
            }
        }
        __syncthreads();

        // ---- B: pos-MLP layer 2 (MFMA): rpe = ph @ pW2 + pb2 ----
        {
#pragma unroll
            for (int mt = 0; mt < 4; ++mt) {
                f32x4 acc = {0.f, 0.f, 0.f, 0.f};
#pragma unroll
                for (int ks = 0; ks < 2; ++ks) {
                    bf16x8 af = *(const bf16x8*)(&ph_s[mt * 16 + lc][ks * 32 + 8 * lg]);
                    acc = mfma16(af, bwp[ks], acc);
                }
#pragma unroll
                for (int r = 0; r < 4; ++r) {
                    int row = mt * 16 + 4 * lg + r;
                    rpe_s[row][dcol] = __float2bfloat16(acc[r] + pb2_r);
                }
            }
        }
        __syncthreads();

        // ---- C: t = q_i - k_j + rpe  (fp32 -> bf16) ----
        {
            int jl = tid >> 3;
            int db = (tid & 7) * 16;
            const float* kp = kg + (b * N_ + jb + jl) * D_ + db;
#pragma unroll
            for (int dd = 0; dd < 16; ++dd) {
                float tv = q_s[db + dd] - kp[dd] + __bfloat162float(rpe_s[jl][db + dd]);
                t_s[jl][db + dd] = __float2bfloat16(tv);
            }
        }
        __syncthreads();

        // ---- D: GEMM1  hidden = relu(t @ aW1 + ab1) ----
        {
#pragma unroll
            for (int nt = 0; nt < 2; ++nt) {
                f32x4 acc1[4];
#pragma unroll
                for (int mt = 0; mt < 4; ++mt) acc1[mt] = {0.f, 0.f, 0.f, 0.f};
#pragma unroll
                for (int ks = 0; ks < 4; ++ks) {
#pragma unroll
                    for (int mt = 0; mt < 4; ++mt) {
                        bf16x8 a = *(const bf16x8*)(&t_s[mt * 16 + lc][ks * 32 + 8 * lg]);
                        acc1[mt] = mfma16(a, bw1[nt][ks], acc1[mt]);
                    }
                }
                float bias = nt ? ab1_1 : ab1_0;
                int col = 32 * w + 16 * nt + lc;
#pragma unroll
                for (int mt = 0; mt < 4; ++mt)
#pragma unroll
                    for (int r = 0; r < 4; ++r) {
                        int row = mt * 16 + 4 * lg + r;
                        hid_s[row][col] = __float2bfloat16(fmaxf(acc1[mt][r] + bias, 0.f));
                    }
            }
        }
        __syncthreads();

        // ---- E: GEMM2  sim = hidden @ aW2 + ab2 (stays in registers) ----
        f32x4 acc2[4];
#pragma unroll
        for (int mt = 0; mt < 4; ++mt) acc2[mt] = {0.f, 0.f, 0.f, 0.f};
#pragma unroll
        for (int ks = 0; ks < 8; ++ks) {
#pragma unroll
            for (int mt = 0; mt < 4; ++mt) {
                bf16x8 a = *(const bf16x8*)(&hid_s[mt * 16 + lc][ks * 32 + 8 * lg]);
                acc2[mt] = mfma16(a, bw2[ks], acc2[mt]);
            }
        }

        // ---- F: online per-channel softmax update ----
        {
            float tmax = -1e30f;
#pragma unroll
            for (int mt = 0; mt < 4; ++mt)
#pragma unroll
                for (int r = 0; r < 4; ++r)
                    tmax = fmaxf(tmax, acc2[mt][r] + ab2_r);
            tmax = fmaxf(tmax, __shfl_xor(tmax, 16));
            tmax = fmaxf(tmax, __shfl_xor(tmax, 32));
            float m_new = fmaxf(m_run, tmax);
            float scale = __expf(m_run - m_new);
            l_run *= scale;
            o_run *= scale;
#pragma unroll
            for (int mt = 0; mt < 4; ++mt)
#pragma unroll
                for (int r = 0; r < 4; ++r) {
                    int row = mt * 16 + 4 * lg + r;
                    float e = __expf(acc2[mt][r] + ab2_r - m_new);
                    float vv = vg[(b * N_ + jb + row) * D_ + dcol]
                             + __bfloat162float(rpe_s[row][dcol]);
                    l_run += e;
                    o_run += e * vv;
                }
            m_run = m_new;
        }
    }

    // ---- final cross-lane-group reduce + write ----
    float lt = l_run + __shfl_xor(l_run, 16);
    lt += __shfl_xor(lt, 32);
    float ot = o_run + __shfl_xor(o_run, 16);
    ot += __shfl_xor(ot, 32);
    if (lg == 0) out[(b * D_ + dcol) * N_ + i] = ot / lt;
}

extern "C" void kernel_launch(void* const* d_in, const int* in_sizes, int n_in,
                              void* d_out, int out_size, void* d_ws, size_t ws_size,
                              hipStream_t stream) {
    const float* x    = (const float*)d_in[0];
    const float* pos  = (const float*)d_in[1];
    const float* Wqkv = (const float*)d_in[2];
    const float* bqkv = (const float*)d_in[3];
    const float* pW1  = (const float*)d_in[4];
    const float* pb1  = (const float*)d_in[5];
    const float* pW2  = (const float*)d_in[6];
    const float* pb2  = (const float*)d_in[7];
    const float* aW1  = (const float*)d_in[8];
    const float* ab1  = (const float*)d_in[9];
    const float* aW2  = (const float*)d_in[10];
    const float* ab2  = (const float*)d_in[11];
    float* out = (float*)d_out;

    float* q = (float*)d_ws;
    float* k = q + B_ * N_ * D_;
    float* v = k + B_ * N_ * D_;
    __hip_bfloat16* aW1T = (__hip_bfloat16*)(v + B_ * N_ * D_);
    __hip_bfloat16* aW2T = aW1T + 256 * 128;
    __hip_bfloat16* pW2T = aW2T + 128 * 256;

    hipLaunchKernelGGL(prep_weights_kernel, dim3(128), dim3(256), 0, stream,
                       aW1, aW2, pW2, aW1T, aW2T, pW2T);
    hipLaunchKernelGGL(qkv_kernel, dim3(3072), dim3(256), 0, stream,
                       x, Wqkv, bqkv, q, k, v);
    hipLaunchKernelGGL(fused_attn_kernel, dim3(2048), dim3(512), 0, stream,
                       q, k, v, pos, pW1, pb1, pW2T, pb2, aW1T, ab1, aW2T, ab2, out);
}

// Round 2
// 365.634 us; speedup vs baseline: 1.0499x; 1.0499x over previous
//
#include <hip/hip_runtime.h>
#include <hip/hip_bf16.h>

#define B_ 4
#define N_ 512
#define D_ 128
#define LOG2E 1.4426950408889634f

typedef __attribute__((ext_vector_type(8))) short bf16x8;
typedef __attribute__((ext_vector_type(4))) float f32x4;

__device__ __forceinline__ f32x4 mfma16(bf16x8 a, bf16x8 b, f32x4 c) {
    return __builtin_amdgcn_mfma_f32_16x16x32_bf16(a, b, c, 0, 0, 0);
}
__device__ __forceinline__ short bf16b(float x) {
    __hip_bfloat16 h = __float2bfloat16(x);
    return *reinterpret_cast<short*>(&h);
}

// ---------------- prep 1: fold + transpose weights ----------------
// aW2T[d][k]  = aW2[k][d] * LOG2E          (128 x 256, bf16)
// pW2T[d][h]  = pW2[h][d]                  (128 x 64,  bf16)
// W12T[n][h]  = sum_d pW2[h][d]*aW1[d][n]  (256 x 64,  bf16)  == (pW2@aW1)^T
// cvec[n]     = ab1[n] + sum_d pb2[d]*aW1[d][n]
__global__ void prep_weights_kernel(const float* __restrict__ aW1, const float* __restrict__ aW2,
                                    const float* __restrict__ pW2, const float* __restrict__ pb2,
                                    const float* __restrict__ ab1,
                                    __hip_bfloat16* __restrict__ aW2T, __hip_bfloat16* __restrict__ pW2T,
                                    __hip_bfloat16* __restrict__ W12T, float* __restrict__ cvec) {
    int idx = blockIdx.x * 256 + threadIdx.x;   // 128 blocks -> 32768
    if (idx < 128 * 256) {
        int n = idx >> 8, k2 = idx & 255;
        aW2T[idx] = __float2bfloat16(aW2[k2 * 128 + n] * LOG2E);
    }
    if (idx < 128 * 64) {
        int n = idx >> 6, k2 = idx & 63;
        pW2T[idx] = __float2bfloat16(pW2[k2 * 128 + n]);
    }
    if (idx < 256 * 64) {
        int n = idx >> 6, h = idx & 63;
        float s = 0.f;
#pragma unroll 8
        for (int d = 0; d < 128; ++d) s += pW2[h * 128 + d] * aW1[d * 256 + n];
        W12T[idx] = __float2bfloat16(s);
    }
    if (idx < 256) {
        float s = ab1[idx];
#pragma unroll 8
        for (int d = 0; d < 128; ++d) s += pb2[d] * aW1[d * 256 + idx];
        cvec[idx] = s;
    }
}

// ---------------- prep 2: qkv = x^T @ Wqkv + bqkv (4 tokens per thread) ----------------
__global__ void qkv_kernel(const float* __restrict__ x, const float* __restrict__ Wqkv,
                           const float* __restrict__ bqkv,
                           float* __restrict__ q, float* __restrict__ k, float* __restrict__ v) {
    int idx = blockIdx.x * 256 + threadIdx.x;   // 768 blocks -> 196608 = 384*512
    int m = idx % 384;
    int g = idx / 384;          // 0..511, group of 4 tokens
    int bn0 = g * 4;
    int b = bn0 >> 9, n0 = bn0 & (N_ - 1);
    const float* xp = x + (b * D_) * N_ + n0;
    float bias = bqkv[m];
    float a0 = bias, a1 = bias, a2 = bias, a3 = bias;
#pragma unroll 4
    for (int d = 0; d < D_; ++d) {
        float wv = Wqkv[d * 384 + m];
        const float4 xv = *reinterpret_cast<const float4*>(xp + d * N_);
        a0 = fmaf(xv.x, wv, a0); a1 = fmaf(xv.y, wv, a1);
        a2 = fmaf(xv.z, wv, a2); a3 = fmaf(xv.w, wv, a3);
    }
    float* dst = (m < 128) ? q : (m < 256 ? k : v);
    int mm = m & 127;
    dst[(bn0 + 0) * D_ + mm] = a0;
    dst[(bn0 + 1) * D_ + mm] = a1;
    dst[(bn0 + 2) * D_ + mm] = a2;
    dst[(bn0 + 3) * D_ + mm] = a3;
}

// ---------------- prep 3: qa = q@aW1, ka = k@aW1 (4 tokens per block) ----------------
__global__ void qka_kernel(const float* __restrict__ q, const float* __restrict__ k,
                           const float* __restrict__ aW1,
                           float* __restrict__ qa, float* __restrict__ ka) {
    int col = threadIdx.x;          // 256
    int bn0 = blockIdx.x * 4;       // 512 blocks
    const float* qp = q + bn0 * D_;
    const float* kp = k + bn0 * D_;
    float aq0 = 0, aq1 = 0, aq2 = 0, aq3 = 0;
    float ak0 = 0, ak1 = 0, ak2 = 0, ak3 = 0;
#pragma unroll 4
    for (int d = 0; d < D_; ++d) {
        float wv = aW1[d * 256 + col];
        aq0 = fmaf(qp[d], wv, aq0);       ak0 = fmaf(kp[d], wv, ak0);
        aq1 = fmaf(qp[D_ + d], wv, aq1);  ak1 = fmaf(kp[D_ + d], wv, ak1);
        aq2 = fmaf(qp[2*D_ + d], wv, aq2); ak2 = fmaf(kp[2*D_ + d], wv, ak2);
        aq3 = fmaf(qp[3*D_ + d], wv, aq3); ak3 = fmaf(kp[3*D_ + d], wv, ak3);
    }
    qa[(bn0 + 0) * 256 + col] = aq0;  ka[(bn0 + 0) * 256 + col] = ak0;
    qa[(bn0 + 1) * 256 + col] = aq1;  ka[(bn0 + 1) * 256 + col] = ak1;
    qa[(bn0 + 2) * 256 + col] = aq2;  ka[(bn0 + 2) * 256 + col] = ak2;
    qa[(bn0 + 3) * 256 + col] = aq3;  ka[(bn0 + 3) * 256 + col] = ak3;
}

// ---------------- main fused kernel: one block per (b,i) ----------------
__global__ __launch_bounds__(512, 4) void fused_attn_kernel(
    const float* __restrict__ qa, const float* __restrict__ ka, const float* __restrict__ vg,
    const float* __restrict__ pos, const float* __restrict__ pW1, const float* __restrict__ pb1,
    const __hip_bfloat16* __restrict__ pW2T, const float* __restrict__ pb2,
    const __hip_bfloat16* __restrict__ W12T, const float* __restrict__ cvec,
    const __hip_bfloat16* __restrict__ aW2T, const float* __restrict__ ab2,
    float* __restrict__ out)
{
    __shared__ __hip_bfloat16 ph_s[64][72];       // 9.2 KB  (144B rows, 16B aligned)
    __shared__ __hip_bfloat16 hid_s[64][264];     // 33.8 KB (528B rows)
    __shared__ float pW1_s[192];
    __shared__ float pb1_s[64];

    const int tid = threadIdx.x;
    const int w  = tid >> 6;      // wave 0..7
    const int l  = tid & 63;
    const int lg = l >> 4;        // lane group 0..3
    const int lc = l & 15;        // lane col 0..15

    const int bi = blockIdx.x;
    const int b  = bi >> 9;
    const int i  = bi & (N_ - 1);

    if (tid < 192) pW1_s[tid] = pW1[tid];
    else if (tid < 256) pb1_s[tid - 192] = pb1[tid - 192];

    const int col0 = 32 * w + lc;   // GEMM1 columns (nt=0); nt=1 -> col0+16
    const int dcol = 16 * w + lc;   // GEMM2 / output channel

    const float qrow0 = qa[(b * N_ + i) * 256 + col0] + cvec[col0];
    const float qrow1 = qa[(b * N_ + i) * 256 + col0 + 16] + cvec[col0 + 16];
    const float ab2_r = ab2[dcol] * LOG2E;
    const float pb2_r = pb2[dcol];

    const float pi0 = pos[(b * N_ + i) * 3 + 0];
    const float pi1 = pos[(b * N_ + i) * 3 + 1];
    const float pi2 = pos[(b * N_ + i) * 3 + 2];

    // persistent B-fragments
    bf16x8 bw12[2][2], bw2[8], bwp[2];
    {
        const bf16x8* p12 = (const bf16x8*)W12T;   // [256 rows][8 vec]
#pragma unroll
        for (int nt = 0; nt < 2; ++nt)
#pragma unroll
            for (int ks = 0; ks < 2; ++ks)
                bw12[nt][ks] = p12[(32 * w + 16 * nt + lc) * 8 + ks * 4 + lg];
        const bf16x8* p2 = (const bf16x8*)aW2T;    // [128 rows][32 vec]
#pragma unroll
        for (int ks = 0; ks < 8; ++ks)
            bw2[ks] = p2[(16 * w + lc) * 32 + ks * 4 + lg];
        const bf16x8* pp = (const bf16x8*)pW2T;    // [128 rows][8 vec]
#pragma unroll
        for (int ks = 0; ks < 2; ++ks)
            bwp[ks] = pp[(16 * w + lc) * 8 + ks * 4 + lg];
    }

    float m_run = -1e30f, l_run = 0.f, o_run = 0.f;

    for (int jt = 0; jt < 8; ++jt) {
        const int jb = jt * 64;
        __syncthreads();   // prior iter fully retired (ph_s safe to overwrite)

        // ---- A: pos-MLP layer 1 (VALU): ph[64][64] ----
        {
            int jl = tid >> 3;
            int hb = (tid & 7) * 8;
            int j = jb + jl;
            float pj0 = pos[(b * N_ + j) * 3 + 0];
            float pj1 = pos[(b * N_ + j) * 3 + 1];
            float pj2 = pos[(b * N_ + j) * 3 + 2];
            float r0 = pi0 - pj0, r1 = pi1 - pj1, r2 = pi2 - pj2;
            bf16x8 tv;
#pragma unroll
            for (int h = 0; h < 8; ++h) {
                int hh = hb + h;
                float a = pb1_s[hh] + r0 * pW1_s[hh] + r1 * pW1_s[64 + hh] + r2 * pW1_s[128 + hh];
                tv[h] = bf16b(fmaxf(a, 0.f));
            }
            *(bf16x8*)(&ph_s[jl][hb]) = tv;
        }
        __syncthreads();

        // ---- B: rpe MFMA (regs) + v prefetch; hidden = relu(ph@W12 + qa_i - ka_j + cvec) ----
        float vv[4][4];
#pragma unroll
        for (int mt = 0; mt < 4; ++mt) {
            f32x4 acc = {0.f, 0.f, 0.f, 0.f};
#pragma unroll
            for (int ks = 0; ks < 2; ++ks) {
                bf16x8 af = *(const bf16x8*)(&ph_s[mt * 16 + lc][ks * 32 + 8 * lg]);
                acc = mfma16(af, bwp[ks], acc);
            }
#pragma unroll
            for (int r = 0; r < 4; ++r) {
                int row = mt * 16 + 4 * lg + r;
                vv[mt][r] = vg[(b * N_ + jb + row) * D_ + dcol] + acc[r] + pb2_r;
            }
        }
#pragma unroll
        for (int nt = 0; nt < 2; ++nt) {
            const int colw = col0 + 16 * nt;
            float kv[4][4];
#pragma unroll
            for (int mt = 0; mt < 4; ++mt)
#pragma unroll
                for (int r = 0; r < 4; ++r)
                    kv[mt][r] = ka[(b * N_ + jb + mt * 16 + 4 * lg + r) * 256 + colw];
            f32x4 acc1[4];
#pragma unroll
            for (int mt = 0; mt < 4; ++mt) acc1[mt] = {0.f, 0.f, 0.f, 0.f};
#pragma unroll
            for (int ks = 0; ks < 2; ++ks)
#pragma unroll
                for (int mt = 0; mt < 4; ++mt) {
                    bf16x8 a = *(const bf16x8*)(&ph_s[mt * 16 + lc][ks * 32 + 8 * lg]);
                    acc1[mt] = mfma16(a, bw12[nt][ks], acc1[mt]);
                }
            const float qv = nt ? qrow1 : qrow0;
#pragma unroll
            for (int mt = 0; mt < 4; ++mt)
#pragma unroll
                for (int r = 0; r < 4; ++r) {
                    int row = mt * 16 + 4 * lg + r;
                    hid_s[row][colw] = __float2bfloat16(fmaxf(acc1[mt][r] + qv - kv[mt][r], 0.f));
                }
        }
        __syncthreads();

        // ---- E: sim' = hid @ aW2T + ab2'  (log2-domain, stays in registers) ----
        f32x4 acc2[4];
#pragma unroll
        for (int mt = 0; mt < 4; ++mt) acc2[mt] = {0.f, 0.f, 0.f, 0.f};
#pragma unroll
        for (int ks = 0; ks < 8; ++ks)
#pragma unroll
            for (int mt = 0; mt < 4; ++mt) {
                bf16x8 a = *(const bf16x8*)(&hid_s[mt * 16 + lc][ks * 32 + 8 * lg]);
                acc2[mt] = mfma16(a, bw2[ks], acc2[mt]);
            }

        // ---- F: online per-channel softmax (base-2 domain) ----
        {
            float tmax = -1e30f;
#pragma unroll
            for (int mt = 0; mt < 4; ++mt)
#pragma unroll
                for (int r = 0; r < 4; ++r) {
                    acc2[mt][r] += ab2_r;
                    tmax = fmaxf(tmax, acc2[mt][r]);
                }
            tmax = fmaxf(tmax, __shfl_xor(tmax, 16));
            tmax = fmaxf(tmax, __shfl_xor(tmax, 32));
            float m_new = fmaxf(m_run, tmax);
            float scale = __builtin_amdgcn_exp2f(m_run - m_new);
            l_run *= scale;
            o_run *= scale;
#pragma unroll
            for (int mt = 0; mt < 4; ++mt)
#pragma unroll
                for (int r = 0; r < 4; ++r) {
                    float e = __builtin_amdgcn_exp2f(acc2[mt][r] - m_new);
                    l_run += e;
                    o_run = fmaf(e, vv[mt][r], o_run);
                }
            m_run = m_new;
        }
    }

    // ---- final cross-lane-group reduce + write ----
    float lt = l_run + __shfl_xor(l_run, 16);
    lt += __shfl_xor(lt, 32);
    float ot = o_run + __shfl_xor(o_run, 16);
    ot += __shfl_xor(ot, 32);
    if (lg == 0) out[(b * D_ + dcol) * N_ + i] = ot / lt;
}

extern "C" void kernel_launch(void* const* d_in, const int* in_sizes, int n_in,
                              void* d_out, int out_size, void* d_ws, size_t ws_size,
                              hipStream_t stream) {
    const float* x    = (const float*)d_in[0];
    const float* pos  = (const float*)d_in[1];
    const float* Wqkv = (const float*)d_in[2];
    const float* bqkv = (const float*)d_in[3];
    const float* pW1  = (const float*)d_in[4];
    const float* pb1  = (const float*)d_in[5];
    const float* pW2  = (const float*)d_in[6];
    const float* pb2  = (const float*)d_in[7];
    const float* aW1  = (const float*)d_in[8];
    const float* ab1  = (const float*)d_in[9];
    const float* aW2  = (const float*)d_in[10];
    const float* ab2  = (const float*)d_in[11];
    float* out = (float*)d_out;

    float* q  = (float*)d_ws;              // 262144
    float* k  = q  + B_ * N_ * D_;         // 262144
    float* v  = k  + B_ * N_ * D_;         // 262144
    float* qa = v  + B_ * N_ * D_;         // 524288
    float* ka = qa + B_ * N_ * 256;        // 524288
    float* cvec = ka + B_ * N_ * 256;      // 256
    __hip_bfloat16* aW2T = (__hip_bfloat16*)(cvec + 256);   // 32768
    __hip_bfloat16* pW2T = aW2T + 128 * 256;                // 8192
    __hip_bfloat16* W12T = pW2T + 128 * 64;                 // 16384

    hipLaunchKernelGGL(prep_weights_kernel, dim3(128), dim3(256), 0, stream,
                       aW1, aW2, pW2, pb2, ab1, aW2T, pW2T, W12T, cvec);
    hipLaunchKernelGGL(qkv_kernel, dim3(768), dim3(256), 0, stream,
                       x, Wqkv, bqkv, q, k, v);
    hipLaunchKernelGGL(qka_kernel, dim3(512), dim3(256), 0, stream,
                       q, k, aW1, qa, ka);
    hipLaunchKernelGGL(fused_attn_kernel, dim3(2048), dim3(512), 0, stream,
                       qa, ka, v, pos, pW1, pb1, pW2T, pb2, W12T, cvec, aW2T, ab2, out);
}

// Round 3
// 347.135 us; speedup vs baseline: 1.1059x; 1.0533x over previous
//
#include <hip/hip_runtime.h>
#include <hip/hip_bf16.h>

#define B_ 4
#define N_ 512
#define D_ 128
#define LOG2E 1.4426950408889634f

typedef __attribute__((ext_vector_type(8))) short bf16x8;
typedef __attribute__((ext_vector_type(4))) float f32x4;

__device__ __forceinline__ f32x4 mfma16(bf16x8 a, bf16x8 b, f32x4 c) {
    return __builtin_amdgcn_mfma_f32_16x16x32_bf16(a, b, c, 0, 0, 0);
}
__device__ __forceinline__ short bf16b(float x) {
    __hip_bfloat16 h = __float2bfloat16(x);
    return *reinterpret_cast<short*>(&h);
}

// ---------------- prep 1: fold + transpose weights ----------------
__global__ void prep_weights_kernel(const float* __restrict__ aW1, const float* __restrict__ aW2,
                                    const float* __restrict__ pW2, const float* __restrict__ pb2,
                                    const float* __restrict__ ab1,
                                    __hip_bfloat16* __restrict__ aW2T, __hip_bfloat16* __restrict__ pW2T,
                                    __hip_bfloat16* __restrict__ W12T, float* __restrict__ cvec) {
    int idx = blockIdx.x * 256 + threadIdx.x;   // 128 blocks -> 32768
    if (idx < 128 * 256) {
        int n = idx >> 8, k2 = idx & 255;
        aW2T[idx] = __float2bfloat16(aW2[k2 * 128 + n] * LOG2E);
    }
    if (idx < 128 * 64) {
        int n = idx >> 6, k2 = idx & 63;
        pW2T[idx] = __float2bfloat16(pW2[k2 * 128 + n]);
    }
    if (idx < 256 * 64) {
        int n = idx >> 6, h = idx & 63;
        float s = 0.f;
#pragma unroll 8
        for (int d = 0; d < 128; ++d) s += pW2[h * 128 + d] * aW1[d * 256 + n];
        W12T[idx] = __float2bfloat16(s);
    }
    if (idx < 256) {
        float s = ab1[idx];
#pragma unroll 8
        for (int d = 0; d < 128; ++d) s += pb2[d] * aW1[d * 256 + idx];
        cvec[idx] = s;
    }
}

// ---------------- prep 2: qkv = x^T @ Wqkv + bqkv ----------------
__global__ void qkv_kernel(const float* __restrict__ x, const float* __restrict__ Wqkv,
                           const float* __restrict__ bqkv,
                           float* __restrict__ q, float* __restrict__ k,
                           __hip_bfloat16* __restrict__ vb) {
    int idx = blockIdx.x * 256 + threadIdx.x;   // 768 blocks -> 196608 = 384*512
    int m = idx % 384;
    int g = idx / 384;          // 0..511, group of 4 tokens
    int bn0 = g * 4;
    int b = bn0 >> 9, n0 = bn0 & (N_ - 1);
    const float* xp = x + (b * D_) * N_ + n0;
    float bias = bqkv[m];
    float a0 = bias, a1 = bias, a2 = bias, a3 = bias;
#pragma unroll 4
    for (int d = 0; d < D_; ++d) {
        float wv = Wqkv[d * 384 + m];
        const float4 xv = *reinterpret_cast<const float4*>(xp + d * N_);
        a0 = fmaf(xv.x, wv, a0); a1 = fmaf(xv.y, wv, a1);
        a2 = fmaf(xv.z, wv, a2); a3 = fmaf(xv.w, wv, a3);
    }
    int mm = m & 127;
    if (m < 256) {
        float* dst = (m < 128) ? q : k;
        dst[(bn0 + 0) * D_ + mm] = a0;
        dst[(bn0 + 1) * D_ + mm] = a1;
        dst[(bn0 + 2) * D_ + mm] = a2;
        dst[(bn0 + 3) * D_ + mm] = a3;
    } else {
        vb[(bn0 + 0) * D_ + mm] = __float2bfloat16(a0);
        vb[(bn0 + 1) * D_ + mm] = __float2bfloat16(a1);
        vb[(bn0 + 2) * D_ + mm] = __float2bfloat16(a2);
        vb[(bn0 + 3) * D_ + mm] = __float2bfloat16(a3);
    }
}

// ---------------- prep 3: qa = q@aW1 (fp32), kab = k@aW1 (bf16) ----------------
__global__ void qka_kernel(const float* __restrict__ q, const float* __restrict__ k,
                           const float* __restrict__ aW1,
                           float* __restrict__ qa, __hip_bfloat16* __restrict__ kab) {
    int col = threadIdx.x;          // 256
    int bn0 = blockIdx.x * 4;       // 512 blocks
    const float* qp = q + bn0 * D_;
    const float* kp = k + bn0 * D_;
    float aq0 = 0, aq1 = 0, aq2 = 0, aq3 = 0;
    float ak0 = 0, ak1 = 0, ak2 = 0, ak3 = 0;
#pragma unroll 4
    for (int d = 0; d < D_; ++d) {
        float wv = aW1[d * 256 + col];
        aq0 = fmaf(qp[d], wv, aq0);        ak0 = fmaf(kp[d], wv, ak0);
        aq1 = fmaf(qp[D_ + d], wv, aq1);   ak1 = fmaf(kp[D_ + d], wv, ak1);
        aq2 = fmaf(qp[2*D_ + d], wv, aq2); ak2 = fmaf(kp[2*D_ + d], wv, ak2);
        aq3 = fmaf(qp[3*D_ + d], wv, aq3); ak3 = fmaf(kp[3*D_ + d], wv, ak3);
    }
    qa[(bn0 + 0) * 256 + col] = aq0;  kab[(bn0 + 0) * 256 + col] = __float2bfloat16(ak0);
    qa[(bn0 + 1) * 256 + col] = aq1;  kab[(bn0 + 1) * 256 + col] = __float2bfloat16(ak1);
    qa[(bn0 + 2) * 256 + col] = aq2;  kab[(bn0 + 2) * 256 + col] = __float2bfloat16(ak2);
    qa[(bn0 + 3) * 256 + col] = aq3;  kab[(bn0 + 3) * 256 + col] = __float2bfloat16(ak3);
}

// ---------------- main fused kernel: one block per (b,i), XCD-swizzled ----------------
__global__ __launch_bounds__(512, 4) void fused_attn_kernel(
    const float* __restrict__ qa, const __hip_bfloat16* __restrict__ kab,
    const __hip_bfloat16* __restrict__ vb,
    const float* __restrict__ pos, const float* __restrict__ pW1, const float* __restrict__ pb1,
    const __hip_bfloat16* __restrict__ pW2T, const float* __restrict__ pb2,
    const __hip_bfloat16* __restrict__ W12T, const float* __restrict__ cvec,
    const __hip_bfloat16* __restrict__ aW2T, const float* __restrict__ ab2,
    float* __restrict__ out)
{
    __shared__ __hip_bfloat16 ph_s[64][72];       // 9.2 KB
    __shared__ __hip_bfloat16 hid_s[64][264];     // 33.8 KB
    __shared__ float pW1_s[192];
    __shared__ float pb1_s[64];

    const int tid = threadIdx.x;
    const int w  = tid >> 6;      // wave 0..7
    const int l  = tid & 63;
    const int lg = l >> 4;        // lane group 0..3
    const int lc = l & 15;        // lane col 0..15

    // XCD-aware swizzle: grid=2048, 8 XCDs, 256 contiguous work items per XCD
    // -> each XCD's L2 holds one half-batch's kab/vb (~0.5 MB)
    const int bi = (blockIdx.x & 7) * 256 + (blockIdx.x >> 3);
    const int b  = bi >> 9;
    const int i  = bi & (N_ - 1);

    if (tid < 192) pW1_s[tid] = pW1[tid];
    else if (tid < 256) pb1_s[tid - 192] = pb1[tid - 192];

    const int col0 = 32 * w + lc;   // GEMM1 columns (nt=0); nt=1 -> col0+16
    const int dcol = 16 * w + lc;   // GEMM2 / output channel

    const float qrow0 = qa[(b * N_ + i) * 256 + col0] + cvec[col0];
    const float qrow1 = qa[(b * N_ + i) * 256 + col0 + 16] + cvec[col0 + 16];
    const float ab2_r = ab2[dcol] * LOG2E;
    const float pb2_r = pb2[dcol];

    const float pi0 = pos[(b * N_ + i) * 3 + 0];
    const float pi1 = pos[(b * N_ + i) * 3 + 1];
    const float pi2 = pos[(b * N_ + i) * 3 + 2];

    // persistent B-fragments
    bf16x8 bw12[2][2], bw2[8], bwp[2];
    {
        const bf16x8* p12 = (const bf16x8*)W12T;   // [256 rows][8 vec]
#pragma unroll
        for (int nt = 0; nt < 2; ++nt)
#pragma unroll
            for (int ks = 0; ks < 2; ++ks)
                bw12[nt][ks] = p12[(32 * w + 16 * nt + lc) * 8 + ks * 4 + lg];
        const bf16x8* p2 = (const bf16x8*)aW2T;    // [128 rows][32 vec]
#pragma unroll
        for (int ks = 0; ks < 8; ++ks)
            bw2[ks] = p2[(16 * w + lc) * 32 + ks * 4 + lg];
        const bf16x8* pp = (const bf16x8*)pW2T;    // [128 rows][8 vec]
#pragma unroll
        for (int ks = 0; ks < 2; ++ks)
            bwp[ks] = pp[(16 * w + lc) * 8 + ks * 4 + lg];
    }

    float m_run = -1e30f, l_run = 0.f, o_run = 0.f;

    for (int jt = 0; jt < 8; ++jt) {
        const int jb = jt * 64;
        __syncthreads();   // prior iter fully retired (ph_s safe to overwrite)

        // ---- A: pos-MLP layer 1 (VALU): ph[64][64] ----
        {
            int jl = tid >> 3;
            int hb = (tid & 7) * 8;
            int j = jb + jl;
            float pj0 = pos[(b * N_ + j) * 3 + 0];
            float pj1 = pos[(b * N_ + j) * 3 + 1];
            float pj2 = pos[(b * N_ + j) * 3 + 2];
            float r0 = pi0 - pj0, r1 = pi1 - pj1, r2 = pi2 - pj2;
            bf16x8 tv;
#pragma unroll
            for (int h = 0; h < 8; ++h) {
                int hh = hb + h;
                float a = pb1_s[hh] + r0 * pW1_s[hh] + r1 * pW1_s[64 + hh] + r2 * pW1_s[128 + hh];
                tv[h] = bf16b(fmaxf(a, 0.f));
            }
            *(bf16x8*)(&ph_s[jl][hb]) = tv;
        }
        __syncthreads();

        // ---- B: hoisted L2 gathers (latency hides under MFMA below) ----
        __hip_bfloat16 vvu[4][4];
        __hip_bfloat16 kvu[2][4][4];
#pragma unroll
        for (int mt = 0; mt < 4; ++mt)
#pragma unroll
            for (int r = 0; r < 4; ++r) {
                int row = mt * 16 + 4 * lg + r;
                vvu[mt][r] = vb[(b * N_ + jb + row) * D_ + dcol];
            }
#pragma unroll
        for (int nt = 0; nt < 2; ++nt)
#pragma unroll
            for (int mt = 0; mt < 4; ++mt)
#pragma unroll
                for (int r = 0; r < 4; ++r) {
                    int row = mt * 16 + 4 * lg + r;
                    kvu[nt][mt][r] = kab[(b * N_ + jb + row) * 256 + col0 + 16 * nt];
                }

        // ---- rpe MFMA (stays in registers) ----
        float vv[4][4];
#pragma unroll
        for (int mt = 0; mt < 4; ++mt) {
            f32x4 acc = {0.f, 0.f, 0.f, 0.f};
#pragma unroll
            for (int ks = 0; ks < 2; ++ks) {
                bf16x8 af = *(const bf16x8*)(&ph_s[mt * 16 + lc][ks * 32 + 8 * lg]);
                acc = mfma16(af, bwp[ks], acc);
            }
#pragma unroll
            for (int r = 0; r < 4; ++r)
                vv[mt][r] = __bfloat162float(vvu[mt][r]) + acc[r] + pb2_r;
        }

        // ---- GEMM1: hidden = relu(ph@W12 + qa_i - ka_j + cvec) ----
#pragma unroll
        for (int nt = 0; nt < 2; ++nt) {
            const int colw = col0 + 16 * nt;
            f32x4 acc1[4];
#pragma unroll
            for (int mt = 0; mt < 4; ++mt) acc1[mt] = {0.f, 0.f, 0.f, 0.f};
#pragma unroll
            for (int ks = 0; ks < 2; ++ks)
#pragma unroll
                for (int mt = 0; mt < 4; ++mt) {
                    bf16x8 a = *(const bf16x8*)(&ph_s[mt * 16 + lc][ks * 32 + 8 * lg]);
                    acc1[mt] = mfma16(a, bw12[nt][ks], acc1[mt]);
                }
            const float qv = nt ? qrow1 : qrow0;
#pragma unroll
            for (int mt = 0; mt < 4; ++mt)
#pragma unroll
                for (int r = 0; r < 4; ++r) {
                    int row = mt * 16 + 4 * lg + r;
                    hid_s[row][colw] = __float2bfloat16(
                        fmaxf(acc1[mt][r] + qv - __bfloat162float(kvu[nt][mt][r]), 0.f));
                }
        }
        __syncthreads();

        // ---- E: sim' = hid @ aW2T + ab2'  (log2-domain, registers) ----
        f32x4 acc2[4];
#pragma unroll
        for (int mt = 0; mt < 4; ++mt) acc2[mt] = {0.f, 0.f, 0.f, 0.f};
#pragma unroll
        for (int ks = 0; ks < 8; ++ks)
#pragma unroll
            for (int mt = 0; mt < 4; ++mt) {
                bf16x8 a = *(const bf16x8*)(&hid_s[mt * 16 + lc][ks * 32 + 8 * lg]);
                acc2[mt] = mfma16(a, bw2[ks], acc2[mt]);
            }

        // ---- F: online per-channel softmax (base-2 domain) ----
        {
            float tmax = -1e30f;
#pragma unroll
            for (int mt = 0; mt < 4; ++mt)
#pragma unroll
                for (int r = 0; r < 4; ++r) {
                    acc2[mt][r] += ab2_r;
                    tmax = fmaxf(tmax, acc2[mt][r]);
                }
            tmax = fmaxf(tmax, __shfl_xor(tmax, 16));
            tmax = fmaxf(tmax, __shfl_xor(tmax, 32));
            float m_new = fmaxf(m_run, tmax);
            float scale = __builtin_amdgcn_exp2f(m_run - m_new);
            l_run *= scale;
            o_run *= scale;
#pragma unroll
            for (int mt = 0; mt < 4; ++mt)
#pragma unroll
                for (int r = 0; r < 4; ++r) {
                    float e = __builtin_amdgcn_exp2f(acc2[mt][r] - m_new);
                    l_run += e;
                    o_run = fmaf(e, vv[mt][r], o_run);
                }
            m_run = m_new;
        }
    }

    // ---- final cross-lane-group reduce + write ----
    float lt = l_run + __shfl_xor(l_run, 16);
    lt += __shfl_xor(lt, 32);
    float ot = o_run + __shfl_xor(o_run, 16);
    ot += __shfl_xor(ot, 32);
    if (lg == 0) out[(b * D_ + dcol) * N_ + i] = ot / lt;
}

extern "C" void kernel_launch(void* const* d_in, const int* in_sizes, int n_in,
                              void* d_out, int out_size, void* d_ws, size_t ws_size,
                              hipStream_t stream) {
    const float* x    = (const float*)d_in[0];
    const float* pos  = (const float*)d_in[1];
    const float* Wqkv = (const float*)d_in[2];
    const float* bqkv = (const float*)d_in[3];
    const float* pW1  = (const float*)d_in[4];
    const float* pb1  = (const float*)d_in[5];
    const float* pW2  = (const float*)d_in[6];
    const float* pb2  = (const float*)d_in[7];
    const float* aW1  = (const float*)d_in[8];
    const float* ab1  = (const float*)d_in[9];
    const float* aW2  = (const float*)d_in[10];
    const float* ab2  = (const float*)d_in[11];
    float* out = (float*)d_out;

    float* q  = (float*)d_ws;              // 262144 f32
    float* k  = q  + B_ * N_ * D_;         // 262144 f32
    float* qa = k  + B_ * N_ * D_;         // 524288 f32
    float* cvec = qa + B_ * N_ * 256;      // 256 f32
    __hip_bfloat16* kab  = (__hip_bfloat16*)(cvec + 256);   // 524288 bf16
    __hip_bfloat16* vb   = kab + B_ * N_ * 256;             // 262144 bf16
    __hip_bfloat16* aW2T = vb + B_ * N_ * D_;               // 32768
    __hip_bfloat16* pW2T = aW2T + 128 * 256;                // 8192
    __hip_bfloat16* W12T = pW2T + 128 * 64;                 // 16384

    hipLaunchKernelGGL(prep_weights_kernel, dim3(128), dim3(256), 0, stream,
                       aW1, aW2, pW2, pb2, ab1, aW2T, pW2T, W12T, cvec);
    hipLaunchKernelGGL(qkv_kernel, dim3(768), dim3(256), 0, stream,
                       x, Wqkv, bqkv, q, k, vb);
    hipLaunchKernelGGL(qka_kernel, dim3(512), dim3(256), 0, stream,
                       q, k, aW1, qa, kab);
    hipLaunchKernelGGL(fused_attn_kernel, dim3(2048), dim3(512), 0, stream,
                       qa, kab, vb, pos, pW1, pb1, pW2T, pb2, W12T, cvec, aW2T, ab2, out);
}

// Round 4
// 239.730 us; speedup vs baseline: 1.6013x; 1.4480x over previous
//
#include <hip/hip_runtime.h>
#include <hip/hip_bf16.h>

#define B_ 4
#define N_ 512
#define D_ 128
#define LOG2E 1.4426950408889634f

typedef __attribute__((ext_vector_type(8))) short bf16x8;
typedef __attribute__((ext_vector_type(4))) short s16x4;
typedef __attribute__((ext_vector_type(4))) float f32x4;

__device__ __forceinline__ f32x4 mfma16(bf16x8 a, bf16x8 b, f32x4 c) {
    return __builtin_amdgcn_mfma_f32_16x16x32_bf16(a, b, c, 0, 0, 0);
}
__device__ __forceinline__ short bf16b(float x) {
    __hip_bfloat16 h = __float2bfloat16(x);
    return *reinterpret_cast<short*>(&h);
}
__device__ __forceinline__ float b2f(short s) {
    unsigned u = ((unsigned)(unsigned short)s) << 16;
    union { unsigned u; float f; } c; c.u = u; return c.f;
}

// ---------------- prep 1: fold + transpose weights ----------------
__global__ void prep_weights_kernel(const float* __restrict__ aW1, const float* __restrict__ aW2,
                                    const float* __restrict__ pW2, const float* __restrict__ pb2,
                                    const float* __restrict__ ab1,
                                    __hip_bfloat16* __restrict__ aW2T, __hip_bfloat16* __restrict__ pW2T,
                                    __hip_bfloat16* __restrict__ W12T, float* __restrict__ cvec) {
    int idx = blockIdx.x * 256 + threadIdx.x;   // 128 blocks -> 32768
    if (idx < 128 * 256) {
        int n = idx >> 8, k2 = idx & 255;
        aW2T[idx] = __float2bfloat16(aW2[k2 * 128 + n] * LOG2E);
    }
    if (idx < 128 * 64) {
        int n = idx >> 6, k2 = idx & 63;
        pW2T[idx] = __float2bfloat16(pW2[k2 * 128 + n]);
    }
    if (idx < 256 * 64) {
        int n = idx >> 6, h = idx & 63;
        float s = 0.f;
#pragma unroll 8
        for (int d = 0; d < 128; ++d) s += pW2[h * 128 + d] * aW1[d * 256 + n];
        W12T[idx] = __float2bfloat16(s);
    }
    if (idx < 256) {
        float s = ab1[idx];
#pragma unroll 8
        for (int d = 0; d < 128; ++d) s += pb2[d] * aW1[d * 256 + idx];
        cvec[idx] = s;
    }
}

// ---------------- prep 2: qkv; v goes straight to MFMA-tiled bf16 ----------------
// vb_t layout: [b][jt][w][mt][lane][r]  (r packed in s16x4, lane*8B coalesced)
__global__ void qkv_kernel(const float* __restrict__ x, const float* __restrict__ Wqkv,
                           const float* __restrict__ bqkv,
                           float* __restrict__ q, float* __restrict__ k,
                           short* __restrict__ vb_t) {
    int idx = blockIdx.x * 256 + threadIdx.x;   // 768 blocks -> 196608 = 384*512
    int m = idx % 384;
    int g = idx / 384;          // 0..511, group of 4 tokens
    int bn0 = g * 4;
    int b = bn0 >> 9, n0 = bn0 & (N_ - 1);
    const float* xp = x + (b * D_) * N_ + n0;
    float bias = bqkv[m];
    float a0 = bias, a1 = bias, a2 = bias, a3 = bias;
#pragma unroll 4
    for (int d = 0; d < D_; ++d) {
        float wv = Wqkv[d * 384 + m];
        const float4 xv = *reinterpret_cast<const float4*>(xp + d * N_);
        a0 = fmaf(xv.x, wv, a0); a1 = fmaf(xv.y, wv, a1);
        a2 = fmaf(xv.z, wv, a2); a3 = fmaf(xv.w, wv, a3);
    }
    int mm = m & 127;
    if (m < 256) {
        float* dst = (m < 128) ? q : k;
        dst[(bn0 + 0) * D_ + mm] = a0;
        dst[(bn0 + 1) * D_ + mm] = a1;
        dst[(bn0 + 2) * D_ + mm] = a2;
        dst[(bn0 + 3) * D_ + mm] = a3;
    } else {
        // n0 % 4 == 0, so tokens n0..n0+3 share (jt, mt, lg); r = t
        int jt = n0 >> 6;
        int mt = (n0 >> 4) & 3;
        int lg = (n0 >> 2) & 3;
        int w  = mm >> 4, lc = mm & 15;
        int l  = lg * 16 + lc;
        s16x4 pk;
        pk[0] = bf16b(a0); pk[1] = bf16b(a1); pk[2] = bf16b(a2); pk[3] = bf16b(a3);
        size_t base = ((((size_t)b * 8 + jt) * 8 + w) * 4 + mt) * 256 + l * 4;
        *(s16x4*)(vb_t + base) = pk;
    }
}

// ---------------- prep 3: qa = q@aW1 (fp32 linear), ka = k@aW1 -> MFMA-tiled bf16 ----
// kab_t layout: [b][jt][w][nt][mt][lane][r]
__global__ void qka_kernel(const float* __restrict__ q, const float* __restrict__ k,
                           const float* __restrict__ aW1,
                           float* __restrict__ qa, short* __restrict__ kab_t) {
    int col = threadIdx.x;          // 256
    int bn0 = blockIdx.x * 4;       // 512 blocks
    int b = bn0 >> 9, n0 = bn0 & (N_ - 1);
    const float* qp = q + bn0 * D_;
    const float* kp = k + bn0 * D_;
    float aq0 = 0, aq1 = 0, aq2 = 0, aq3 = 0;
    float ak0 = 0, ak1 = 0, ak2 = 0, ak3 = 0;
#pragma unroll 4
    for (int d = 0; d < D_; ++d) {
        float wv = aW1[d * 256 + col];
        aq0 = fmaf(qp[d], wv, aq0);        ak0 = fmaf(kp[d], wv, ak0);
        aq1 = fmaf(qp[D_ + d], wv, aq1);   ak1 = fmaf(kp[D_ + d], wv, ak1);
        aq2 = fmaf(qp[2*D_ + d], wv, aq2); ak2 = fmaf(kp[2*D_ + d], wv, ak2);
        aq3 = fmaf(qp[3*D_ + d], wv, aq3); ak3 = fmaf(kp[3*D_ + d], wv, ak3);
    }
    qa[(bn0 + 0) * 256 + col] = aq0;
    qa[(bn0 + 1) * 256 + col] = aq1;
    qa[(bn0 + 2) * 256 + col] = aq2;
    qa[(bn0 + 3) * 256 + col] = aq3;
    int jt = n0 >> 6;
    int mt = (n0 >> 4) & 3;
    int lg = (n0 >> 2) & 3;
    int w  = col >> 5, nt = (col >> 4) & 1, lc = col & 15;
    int l  = lg * 16 + lc;
    s16x4 pk;
    pk[0] = bf16b(ak0); pk[1] = bf16b(ak1); pk[2] = bf16b(ak2); pk[3] = bf16b(ak3);
    size_t base = (((((size_t)b * 8 + jt) * 8 + w) * 2 + nt) * 4 + mt) * 256 + l * 4;
    *(s16x4*)(kab_t + base) = pk;
}

// ---------------- main fused kernel: one block per (b,i), XCD-swizzled ----------------
__global__ __launch_bounds__(512, 4) void fused_attn_kernel(
    const float* __restrict__ qa, const short* __restrict__ kab_t,
    const short* __restrict__ vb_t,
    const float* __restrict__ pos, const float* __restrict__ pW1, const float* __restrict__ pb1,
    const __hip_bfloat16* __restrict__ pW2T, const float* __restrict__ pb2,
    const __hip_bfloat16* __restrict__ W12T, const float* __restrict__ cvec,
    const __hip_bfloat16* __restrict__ aW2T, const float* __restrict__ ab2,
    float* __restrict__ out)
{
    __shared__ __hip_bfloat16 ph_s[64][72];       // 9.2 KB
    __shared__ __hip_bfloat16 hid_s[64][264];     // 33.8 KB
    __shared__ float pW1_s[192];
    __shared__ float pb1_s[64];

    const int tid = threadIdx.x;
    const int w  = tid >> 6;      // wave 0..7
    const int l  = tid & 63;
    const int lg = l >> 4;        // lane group 0..3
    const int lc = l & 15;        // lane col 0..15

    // XCD-aware swizzle: grid=2048, 8 XCDs, 256 contiguous work items per XCD
    const int bi = (blockIdx.x & 7) * 256 + (blockIdx.x >> 3);
    const int b  = bi >> 9;
    const int i  = bi & (N_ - 1);

    if (tid < 192) pW1_s[tid] = pW1[tid];
    else if (tid < 256) pb1_s[tid - 192] = pb1[tid - 192];

    const int col0 = 32 * w + lc;   // GEMM1 columns (nt=0); nt=1 -> col0+16
    const int dcol = 16 * w + lc;   // GEMM2 / output channel

    const float qrow0 = qa[(b * N_ + i) * 256 + col0] + cvec[col0];
    const float qrow1 = qa[(b * N_ + i) * 256 + col0 + 16] + cvec[col0 + 16];
    const float ab2_r = ab2[dcol] * LOG2E;
    const float pb2_r = pb2[dcol];

    const float pi0 = pos[(b * N_ + i) * 3 + 0];
    const float pi1 = pos[(b * N_ + i) * 3 + 1];
    const float pi2 = pos[(b * N_ + i) * 3 + 2];

    // persistent B-fragments
    bf16x8 bw12[2][2], bw2[8], bwp[2];
    {
        const bf16x8* p12 = (const bf16x8*)W12T;   // [256 rows][8 vec]
#pragma unroll
        for (int nt = 0; nt < 2; ++nt)
#pragma unroll
            for (int ks = 0; ks < 2; ++ks)
                bw12[nt][ks] = p12[(32 * w + 16 * nt + lc) * 8 + ks * 4 + lg];
        const bf16x8* p2 = (const bf16x8*)aW2T;    // [128 rows][32 vec]
#pragma unroll
        for (int ks = 0; ks < 8; ++ks)
            bw2[ks] = p2[(16 * w + lc) * 32 + ks * 4 + lg];
        const bf16x8* pp = (const bf16x8*)pW2T;    // [128 rows][8 vec]
#pragma unroll
        for (int ks = 0; ks < 2; ++ks)
            bwp[ks] = pp[(16 * w + lc) * 8 + ks * 4 + lg];
    }

    float m_run = -1e30f, l_run = 0.f, o_run = 0.f;

    // per-wave tiled-load bases (advance by fixed stride per jt)
    const short* ktp0 = kab_t + (((size_t)b * 8) * 8 + w) * 2048 + l * 4;  // + jt*16384
    const short* vtp0 = vb_t  + (((size_t)b * 8) * 8 + w) * 1024 + l * 4;  // + jt*8192

    for (int jt = 0; jt < 8; ++jt) {
        const int jb = jt * 64;
        __syncthreads();   // prior iter fully retired (ph_s safe to overwrite)

        // ---- A: pos-MLP layer 1 (VALU): ph[64][64] ----
        {
            int jl = tid >> 3;
            int hb = (tid & 7) * 8;
            int j = jb + jl;
            float pj0 = pos[(b * N_ + j) * 3 + 0];
            float pj1 = pos[(b * N_ + j) * 3 + 1];
            float pj2 = pos[(b * N_ + j) * 3 + 2];
            float r0 = pi0 - pj0, r1 = pi1 - pj1, r2 = pi2 - pj2;
            bf16x8 tv;
#pragma unroll
            for (int h = 0; h < 8; ++h) {
                int hh = hb + h;
                float a = pb1_s[hh] + r0 * pW1_s[hh] + r1 * pW1_s[64 + hh] + r2 * pW1_s[128 + hh];
                tv[h] = bf16b(fmaxf(a, 0.f));
            }
            *(bf16x8*)(&ph_s[jl][hb]) = tv;
        }
        __syncthreads();

        // ---- B: coalesced tiled loads (8B/lane, 512B/wave-instr) ----
        const short* ktp = ktp0 + (size_t)jt * 16384;
        const short* vtp = vtp0 + (size_t)jt * 8192;
        s16x4 kv4[2][4], vv4[4];
#pragma unroll
        for (int mt = 0; mt < 4; ++mt)
            vv4[mt] = *(const s16x4*)(vtp + mt * 256);
#pragma unroll
        for (int nt = 0; nt < 2; ++nt)
#pragma unroll
            for (int mt = 0; mt < 4; ++mt)
                kv4[nt][mt] = *(const s16x4*)(ktp + nt * 1024 + mt * 256);

        // ---- rpe MFMA (stays in registers) ----
        float vv[4][4];
#pragma unroll
        for (int mt = 0; mt < 4; ++mt) {
            f32x4 acc = {0.f, 0.f, 0.f, 0.f};
#pragma unroll
            for (int ks = 0; ks < 2; ++ks) {
                bf16x8 af = *(const bf16x8*)(&ph_s[mt * 16 + lc][ks * 32 + 8 * lg]);
                acc = mfma16(af, bwp[ks], acc);
            }
#pragma unroll
            for (int r = 0; r < 4; ++r)
                vv[mt][r] = b2f(vv4[mt][r]) + acc[r] + pb2_r;
        }

        // ---- GEMM1: hidden = relu(ph@W12 + qa_i - ka_j + cvec) ----
#pragma unroll
        for (int nt = 0; nt < 2; ++nt) {
            const int colw = col0 + 16 * nt;
            f32x4 acc1[4];
#pragma unroll
            for (int mt = 0; mt < 4; ++mt) acc1[mt] = {0.f, 0.f, 0.f, 0.f};
#pragma unroll
            for (int ks = 0; ks < 2; ++ks)
#pragma unroll
                for (int mt = 0; mt < 4; ++mt) {
                    bf16x8 a = *(const bf16x8*)(&ph_s[mt * 16 + lc][ks * 32 + 8 * lg]);
                    acc1[mt] = mfma16(a, bw12[nt][ks], acc1[mt]);
                }
            const float qv = nt ? qrow1 : qrow0;
#pragma unroll
            for (int mt = 0; mt < 4; ++mt)
#pragma unroll
                for (int r = 0; r < 4; ++r) {
                    int row = mt * 16 + 4 * lg + r;
                    hid_s[row][colw] = __float2bfloat16(
                        fmaxf(acc1[mt][r] + qv - b2f(kv4[nt][mt][r]), 0.f));
                }
        }
        __syncthreads();

        // ---- E: sim' = hid @ aW2T + ab2'  (log2-domain, registers) ----
        f32x4 acc2[4];
#pragma unroll
        for (int mt = 0; mt < 4; ++mt) acc2[mt] = {0.f, 0.f, 0.f, 0.f};
#pragma unroll
        for (int ks = 0; ks < 8; ++ks)
#pragma unroll
            for (int mt = 0; mt < 4; ++mt) {
                bf16x8 a = *(const bf16x8*)(&hid_s[mt * 16 + lc][ks * 32 + 8 * lg]);
                acc2[mt] = mfma16(a, bw2[ks], acc2[mt]);
            }

        // ---- F: online per-channel softmax (base-2 domain) ----
        {
            float tmax = -1e30f;
#pragma unroll
            for (int mt = 0; mt < 4; ++mt)
#pragma unroll
                for (int r = 0; r < 4; ++r) {
                    acc2[mt][r] += ab2_r;
                    tmax = fmaxf(tmax, acc2[mt][r]);
                }
            tmax = fmaxf(tmax, __shfl_xor(tmax, 16));
            tmax = fmaxf(tmax, __shfl_xor(tmax, 32));
            float m_new = fmaxf(m_run, tmax);
            float scale = __builtin_amdgcn_exp2f(m_run - m_new);
            l_run *= scale;
            o_run *= scale;
#pragma unroll
            for (int mt = 0; mt < 4; ++mt)
#pragma unroll
                for (int r = 0; r < 4; ++r) {
                    float e = __builtin_amdgcn_exp2f(acc2[mt][r] - m_new);
                    l_run += e;
                    o_run = fmaf(e, vv[mt][r], o_run);
                }
            m_run = m_new;
        }
    }

    // ---- final cross-lane-group reduce + write ----
    float lt = l_run + __shfl_xor(l_run, 16);
    lt += __shfl_xor(lt, 32);
    float ot = o_run + __shfl_xor(o_run, 16);
    ot += __shfl_xor(ot, 32);
    if (lg == 0) out[(b * D_ + dcol) * N_ + i] = ot / lt;
}

extern "C" void kernel_launch(void* const* d_in, const int* in_sizes, int n_in,
                              void* d_out, int out_size, void* d_ws, size_t ws_size,
                              hipStream_t stream) {
    const float* x    = (const float*)d_in[0];
    const float* pos  = (const float*)d_in[1];
    const float* Wqkv = (const float*)d_in[2];
    const float* bqkv = (const float*)d_in[3];
    const float* pW1  = (const float*)d_in[4];
    const float* pb1  = (const float*)d_in[5];
    const float* pW2  = (const float*)d_in[6];
    const float* pb2  = (const float*)d_in[7];
    const float* aW1  = (const float*)d_in[8];
    const float* ab1  = (const float*)d_in[9];
    const float* aW2  = (const float*)d_in[10];
    const float* ab2  = (const float*)d_in[11];
    float* out = (float*)d_out;

    float* q  = (float*)d_ws;              // 262144 f32
    float* k  = q  + B_ * N_ * D_;         // 262144 f32
    float* qa = k  + B_ * N_ * D_;         // 524288 f32
    float* cvec = qa + B_ * N_ * 256;      // 256 f32
    short* kab_t = (short*)(cvec + 256);   // 524288 bf16 (tiled)
    short* vb_t  = kab_t + B_ * N_ * 256;  // 262144 bf16 (tiled)
    __hip_bfloat16* aW2T = (__hip_bfloat16*)(vb_t + B_ * N_ * D_);  // 32768
    __hip_bfloat16* pW2T = aW2T + 128 * 256;                        // 8192
    __hip_bfloat16* W12T = pW2T + 128 * 64;                         // 16384

    hipLaunchKernelGGL(prep_weights_kernel, dim3(128), dim3(256), 0, stream,
                       aW1, aW2, pW2, pb2, ab1, aW2T, pW2T, W12T, cvec);
    hipLaunchKernelGGL(qkv_kernel, dim3(768), dim3(256), 0, stream,
                       x, Wqkv, bqkv, q, k, vb_t);
    hipLaunchKernelGGL(qka_kernel, dim3(512), dim3(256), 0, stream,
                       q, k, aW1, qa, kab_t);
    hipLaunchKernelGGL(fused_attn_kernel, dim3(2048), dim3(512), 0, stream,
                       qa, kab_t, vb_t, pos, pW1, pb1, pW2T, pb2, W12T, cvec, aW2T, ab2, out);
}